// Round 9
// baseline (209.757 us; speedup 1.0000x reference)
//
#include <hip/hip_runtime.h>
#include <hip/hip_bf16.h>
#include <math.h>

// Problem constants
#define B_    4
#define C_IN_ 128
#define N_    2048
#define NSEL_ 1024
#define H_    4
#define KS_   2            // key-split chunks (1024 keys = 16 tiles of 64 each)

typedef __bf16 bf16;
typedef __bf16 bf16x2 __attribute__((ext_vector_type(2)));
typedef __bf16 bf16x4 __attribute__((ext_vector_type(4)));
typedef __bf16 bf16x8 __attribute__((ext_vector_type(8)));
typedef float  f32x4  __attribute__((ext_vector_type(4)));

// ---------------------------------------------------------------------------
// Kernel 0 (prep): W fp32 -> bf16 (Wbf, 4x256x128); inverse permutation.
// ---------------------------------------------------------------------------
__global__ __launch_bounds__(256) void prep_kernel(
    const int* __restrict__ isel, const int* __restrict__ idrp,
    const float* __restrict__ Wq, const float* __restrict__ Wk,
    const float* __restrict__ Wv, const float* __restrict__ Ws,
    int* __restrict__ inv, bf16* __restrict__ Wbf)
{
    const int blk = blockIdx.x;
    if (blk < 128) {
        int e = blk * 256 + threadIdx.x;
        int which = e >> 13, idx = e & 8191;
        const float* Wx = (which == 0) ? Wq : (which == 1) ? Wk
                        : (which == 2) ? Wv : Ws;
        float4 v = *(const float4*)(Wx + (size_t)idx * 4);
        bf16x4 o; o[0] = (bf16)v.x; o[1] = (bf16)v.y; o[2] = (bf16)v.z; o[3] = (bf16)v.w;
        *(bf16x4*)(Wbf + (size_t)which * 32768 + (size_t)idx * 4) = o;
    } else {
        int g = (blk - 128) * 256 + threadIdx.x;
        int b = g >> 11, j = g & (N_ - 1);
        int pos = (j < NSEL_) ? isel[b * NSEL_ + j] : idrp[b * NSEL_ + (j - NSEL_)];
        inv[b * N_ + (pos & (N_ - 1))] = j;
    }
}

// ---------------------------------------------------------------------------
// Kernel 1: QKV + skip MFMA GEMM (grid (32, 8, B)). For Q/K the MFMA operands
// are SWAPPED (A=x, B=W) so the C layout puts d across lanes -> 32B-coalesced
// epilogue stores. Staging packs bf16 pairs -> b32 LDS writes.
//   qT : (bh, n, 64) bf16, Q pre-scaled 1/8
//   kTt: (bh, tile, key&63, d) bf16 8KB tiles;  vTt: (bh, tile, dv, key&63)
//   skip: bf16 -> skip_ws (natural order)
// ---------------------------------------------------------------------------
#define XSTR 136

__global__ __launch_bounds__(256) void qkv_mfma_kernel(
    const float* __restrict__ pcd, const float* __restrict__ sel,
    const float* __restrict__ drop, const bf16* __restrict__ Wbf,
    bf16* __restrict__ qT, bf16* __restrict__ kTt, bf16* __restrict__ vTt,
    bf16* __restrict__ skipw)
{
    const int ntile = blockIdx.x;
    const int which = blockIdx.y >> 1;   // 0=Q 1=K 2=V 3=skip
    const int rh    = blockIdx.y & 1;    // 128-row half
    const int b     = blockIdx.z;
    const int tid   = threadIdx.x;
    const int w     = tid >> 6;
    const int lane  = tid & 63;
    const int quad  = lane >> 4;
    const int lc    = lane & 15;
    const int n0    = ntile * 64;

    __shared__ __align__(16) bf16 xT[64 * XSTR];

    const float* srcp; int rstride;
    if (which == 3)      { srcp = pcd  + (size_t)b * C_IN_ * N_ + n0;              rstride = N_;    }
    else if (ntile < 16) { srcp = sel  + (size_t)b * C_IN_ * NSEL_ + n0;           rstride = NSEL_; }
    else                 { srcp = drop + (size_t)b * C_IN_ * NSEL_ + (n0 - NSEL_); rstride = NSEL_; }

    // Stage x fp32 [c][n] -> bf16 xT [n][c ^ swz] with PAIRED-c b32 writes.
    #pragma unroll
    for (int k = 0; k < 4; ++k) {
        int e  = tid + k * 256;          // 0..1023
        int cp = e >> 4, nq = e & 15;    // c-pair 0..63
        int c0 = cp * 2;
        float4 v0 = *(const float4*)(srcp + (size_t)c0 * rstride + nq * 4);
        float4 v1 = *(const float4*)(srcp + (size_t)(c0 + 1) * rstride + nq * 4);
        int cc = c0 ^ ((nq & 3) << 3);   // swizzle key = ((n>>2)&3)<<3, n>>2 == nq
        float a0[4] = {v0.x, v0.y, v0.z, v0.w};
        float a1[4] = {v1.x, v1.y, v1.z, v1.w};
        #pragma unroll
        for (int i = 0; i < 4; ++i) {
            int n = nq * 4 + i;
            bf16x2 t; t[0] = (bf16)a0[i]; t[1] = (bf16)a1[i];
            *(bf16x2*)&xT[n * XSTR + cc] = t;
        }
    }
    __syncthreads();

    const bf16* wbase = Wbf + (size_t)which * 256 * 128;
    const int rbase = rh * 128 + w * 32;     // wave's 32 output rows

    f32x4 acc[8];
    #pragma unroll
    for (int i = 0; i < 8; ++i) acc[i] = (f32x4){0.f, 0.f, 0.f, 0.f};

    #pragma unroll
    for (int kq = 0; kq < 4; ++kq) {
        bf16x8 wf[2], xA[4];
        #pragma unroll
        for (int ot = 0; ot < 2; ++ot)
            wf[ot] = *(const bf16x8*)(wbase + (size_t)(rbase + ot * 16 + lc) * 128 + kq * 32 + quad * 8);
        #pragma unroll
        for (int nt = 0; nt < 4; ++nt) {
            int row = nt * 16 + lc;
            int col = (kq * 32 + quad * 8) ^ (((row >> 2) & 3) << 3);
            xA[nt] = *(const bf16x8*)&xT[row * XSTR + col];
        }
        if (which <= 1) {   // swapped: A=x (m=n), B=W (col=o)
            #pragma unroll
            for (int nt = 0; nt < 4; ++nt)
                #pragma unroll
                for (int ot = 0; ot < 2; ++ot)
                    acc[nt * 2 + ot] = __builtin_amdgcn_mfma_f32_16x16x32_bf16(xA[nt], wf[ot], acc[nt * 2 + ot], 0, 0, 0);
        } else {            // normal: A=W (m=o), B=x (col=n)
            #pragma unroll
            for (int ot = 0; ot < 2; ++ot)
                #pragma unroll
                for (int nt = 0; nt < 4; ++nt)
                    acc[ot * 4 + nt] = __builtin_amdgcn_mfma_f32_16x16x32_bf16(wf[ot], xA[nt], acc[ot * 4 + nt], 0, 0, 0);
        }
    }

    if (which <= 1) {
        // C: row=n-local (quad*4+r), col=o-local (lc) -> d-contiguous stores.
        #pragma unroll
        for (int nt = 0; nt < 4; ++nt) {
            #pragma unroll
            for (int ot = 0; ot < 2; ++ot) {
                #pragma unroll
                for (int r = 0; r < 4; ++r) {
                    int n    = n0 + nt * 16 + quad * 4 + r;
                    int rloc = nt * 16 + quad * 4 + r;
                    int o256 = rbase + ot * 16 + lc;
                    int h = o256 >> 6, d = o256 & 63;
                    float val = acc[nt * 2 + ot][r];
                    if (which == 0)
                        qT[((size_t)(b * H_ + h) * N_ + n) * 64 + d] = (bf16)(val * 0.125f);
                    else
                        kTt[(((size_t)(b * H_ + h) * 32 + ntile) << 12) | (rloc << 6) | d] = (bf16)val;
                }
            }
        }
    } else {
        // C: row=o-local, col=n-local (lc) -> n-contiguous stores.
        #pragma unroll
        for (int ot = 0; ot < 2; ++ot) {
            #pragma unroll
            for (int nt = 0; nt < 4; ++nt) {
                #pragma unroll
                for (int r = 0; r < 4; ++r) {
                    int o256 = rbase + ot * 16 + quad * 4 + r;
                    int n    = n0 + nt * 16 + lc;
                    int rloc = nt * 16 + lc;
                    float val = acc[ot * 4 + nt][r];
                    if (which == 2) {
                        int h = o256 >> 6, dv = o256 & 63;
                        vTt[(((size_t)(b * H_ + h) * 32 + ntile) << 12) | (dv << 6) | rloc] = (bf16)val;
                    } else {
                        skipw[((size_t)b * 256 + o256) * N_ + n] = (bf16)val;
                    }
                }
            }
        }
    }
}

// ---------------------------------------------------------------------------
// Kernel 2: key-split flash attention, ONE WAVE PER BLOCK, no barriers.
// K/V read direct global->reg (pre-tiled coalesced layout, XCD-local L2),
// one-tile register prefetch. P transposed via tiny per-block LDS strip.
// grid 4096 x 64 thr: id -> bh=(id&7)+8*((id>>3)&1), qtile=(id>>4)&127, c=id>>11.
// ---------------------------------------------------------------------------
#define PSTR 72

__global__ __launch_bounds__(64, 4) void attn_kernel(
    const bf16* __restrict__ qT, const bf16* __restrict__ kTt,
    const bf16* __restrict__ vTt, bf16* __restrict__ Opart,
    float* __restrict__ S_ws)
{
    const int id    = blockIdx.x;
    const int bh    = (id & 7) + 8 * ((id >> 3) & 1);
    const int qtile = (id >> 4) & 127;
    const int c     = id >> 11;          // 0..KS_-1
    const int b     = bh >> 2;
    const int h     = bh & 3;
    const int lane  = threadIdx.x;
    const int quad  = lane >> 4;
    const int lc    = lane & 15;
    const int n0    = qtile * 16;

    __shared__ __align__(16) bf16 pw[16 * PSTR];   // 2304 B

    const bf16* qp = qT + ((size_t)bh * N_ + n0 + lc) * 64 + quad * 8;
    bf16x8 aq0 = *(const bf16x8*)(qp);
    bf16x8 aq1 = *(const bf16x8*)(qp + 32);

    const bf16* kbase = kTt + (((size_t)bh * 32 + c * 16) << 12);
    const bf16* vbase = vTt + (((size_t)bh * 32 + c * 16) << 12);
    const int fo = lc * 64 + quad * 8;   // fragment load offset within a tile row-group

    // prologue: K fragments for tile 0
    bf16x8 kf[4][2];
    #pragma unroll
    for (int mt = 0; mt < 4; ++mt) {
        kf[mt][0] = *(const bf16x8*)(kbase + mt * 1024 + fo);
        kf[mt][1] = *(const bf16x8*)(kbase + mt * 1024 + fo + 32);
    }

    f32x4 accO[4];
    #pragma unroll
    for (int i = 0; i < 4; ++i) accO[i] = (f32x4){0.f, 0.f, 0.f, 0.f};
    float psum[4] = {0.f, 0.f, 0.f, 0.f};

    for (int s = 0; s < 16; ++s) {
        // ---- S = (Q/8)^T K with prefetched kf ----
        f32x4 accS[4];
        #pragma unroll
        for (int mt = 0; mt < 4; ++mt) {
            f32x4 z = (f32x4){0.f, 0.f, 0.f, 0.f};
            z = __builtin_amdgcn_mfma_f32_16x16x32_bf16(aq0, kf[mt][0], z, 0, 0, 0);
            z = __builtin_amdgcn_mfma_f32_16x16x32_bf16(aq1, kf[mt][1], z, 0, 0, 0);
            accS[mt] = z;
        }

        // ---- issue V(s) + K(s+1) loads; land during exp/P phase ----
        bf16x8 vf[4][2];
        const bf16* vg = vbase + ((size_t)s << 12);
        #pragma unroll
        for (int dvt = 0; dvt < 4; ++dvt) {
            vf[dvt][0] = *(const bf16x8*)(vg + dvt * 1024 + fo);
            vf[dvt][1] = *(const bf16x8*)(vg + dvt * 1024 + fo + 32);
        }
        const bf16* kg = kbase + ((size_t)((s + 1) & 15) << 12);
        #pragma unroll
        for (int mt = 0; mt < 4; ++mt) {
            kf[mt][0] = *(const bf16x8*)(kg + mt * 1024 + fo);
            kf[mt][1] = *(const bf16x8*)(kg + mt * 1024 + fo + 32);
        }

        // ---- P = exp(S), per-lane row partial sums ----
        #pragma unroll
        for (int r = 0; r < 4; ++r) {
            float sum = 0.f;
            #pragma unroll
            for (int mt = 0; mt < 4; ++mt) {
                float p = __expf(accS[mt][r]);
                accS[mt][r] = p;
                sum += p;
            }
            psum[r] += sum;
        }

        // ---- P: C layout -> LDS strip -> A layout (per-wave, no barrier) ----
        #pragma unroll
        for (int mt = 0; mt < 4; ++mt)
            #pragma unroll
            for (int r = 0; r < 4; ++r)
                pw[(quad * 4 + r) * PSTR + mt * 16 + lc] = (bf16)accS[mt][r];
        bf16x8 ap0 = *(const bf16x8*)(&pw[lc * PSTR + quad * 8]);
        bf16x8 ap1 = *(const bf16x8*)(&pw[lc * PSTR + 32 + quad * 8]);

        // ---- O += P * V^T ----
        #pragma unroll
        for (int dvt = 0; dvt < 4; ++dvt) {
            accO[dvt] = __builtin_amdgcn_mfma_f32_16x16x32_bf16(ap0, vf[dvt][0], accO[dvt], 0, 0, 0);
            accO[dvt] = __builtin_amdgcn_mfma_f32_16x16x32_bf16(ap1, vf[dvt][1], accO[dvt], 0, 0, 0);
        }
    }

    // ---- chunk denominators + chunk-normalized O ----
    float inv[4];
    #pragma unroll
    for (int r = 0; r < 4; ++r) {
        float s = psum[r];
        #pragma unroll
        for (int off = 1; off < 16; off <<= 1)
            s += __shfl_xor(s, off, 64);
        inv[r] = 1.f / s;
        int n = n0 + quad * 4 + r;
        if (lc == 0)
            S_ws[((size_t)(c * B_ + b) * H_ + h) * N_ + n] = s;
    }

    #pragma unroll
    for (int r = 0; r < 4; ++r) {
        int n = n0 + quad * 4 + r;
        #pragma unroll
        for (int dvt = 0; dvt < 4; ++dvt) {
            int o = h * 64 + dvt * 16 + lc;
            Opart[((size_t)(c * B_ + b) * N_ + n) * 256 + o] = (bf16)(accO[dvt][r] * inv[r]);
        }
    }
}

// ---------------------------------------------------------------------------
// Kernel 3: merge KS chunks + permutation scatter + skip add. Pure writes to
// out (skip read from bf16 ws; no RMW read of out).
// grid (32 pos-tiles, 4 og(=h), B), 256 thr.
// ---------------------------------------------------------------------------
__global__ __launch_bounds__(256) void scatter_kernel(
    const bf16* __restrict__ Opart, const float* __restrict__ S_ws,
    const int* __restrict__ inv, const bf16* __restrict__ skipw,
    float* __restrict__ out)
{
    const int ptile = blockIdx.x;
    const int og    = blockIdx.y;     // == head h
    const int b     = blockIdx.z;
    const int tid   = threadIdx.x;
    const int p0    = ptile * 64;

    __shared__ __align__(16) bf16 lds[64 * 72];
    __shared__ float wls[KS_][64];
    __shared__ int   jrow[64];

    if (tid < 64) {
        int row = tid;
        int j = inv[b * N_ + p0 + row] & (N_ - 1);
        jrow[row] = j;
        float sv[KS_]; float denom = 0.f;
        #pragma unroll
        for (int c = 0; c < KS_; ++c) {
            sv[c] = S_ws[((size_t)(c * B_ + b) * H_ + og) * N_ + j];
            denom += sv[c];
        }
        float id = 1.f / denom;
        #pragma unroll
        for (int c = 0; c < KS_; ++c) wls[c][row] = sv[c] * id;
    }
    __syncthreads();

    #pragma unroll
    for (int k = 0; k < 2; ++k) {
        int e = tid + k * 256;
        int row = e >> 3, seg = e & 7;
        int j = jrow[row];
        float a8[8];
        #pragma unroll
        for (int i = 0; i < 8; ++i) a8[i] = 0.f;
        #pragma unroll
        for (int c = 0; c < KS_; ++c) {
            bf16x8 v = *(const bf16x8*)(Opart + ((size_t)(c * B_ + b) * N_ + j) * 256 + og * 64 + seg * 8);
            float wgt = wls[c][row];
            #pragma unroll
            for (int i = 0; i < 8; ++i) a8[i] += wgt * (float)v[i];
        }
        bf16x8 o8;
        #pragma unroll
        for (int i = 0; i < 8; ++i) o8[i] = (bf16)a8[i];
        *(bf16x8*)&lds[row * 72 + seg * 8] = o8;
    }
    __syncthreads();

    const int pl  = tid & 63;
    const int og2 = tid >> 6;
    #pragma unroll
    for (int k = 0; k < 8; ++k) {
        int o_loc = og2 * 16 + k * 2;
        bf16x2 v2 = *(const bf16x2*)&lds[pl * 72 + o_loc];
        int o = og * 64 + o_loc;
        size_t a = ((size_t)b * 256 + o) * N_ + p0 + pl;
        float s0 = (float)skipw[a];
        float s1 = (float)skipw[a + N_];
        out[a]      = s0 + (float)v2[0];
        out[a + N_] = s1 + (float)v2[1];
    }
}

// ---------------------------------------------------------------------------
extern "C" void kernel_launch(void* const* d_in, const int* in_sizes, int n_in,
                              void* d_out, int out_size, void* d_ws, size_t ws_size,
                              hipStream_t stream) {
    const float* pcd  = (const float*)d_in[0];
    const float* sel  = (const float*)d_in[1];
    const float* drop = (const float*)d_in[2];
    const int*   isel = (const int*)d_in[3];
    const int*   idrp = (const int*)d_in[4];
    const float* Wq   = (const float*)d_in[5];
    const float* Wk   = (const float*)d_in[6];
    const float* Wv   = (const float*)d_in[7];
    const float* Ws   = (const float*)d_in[8];
    float* out = (float*)d_out;

    const size_t MB = 1024 * 1024;
    // ws: qT 4 | kTt 4 | vTt 4 | Opart 8 (KS2) | skipw 4.5 | S_ws 256K | inv 32K
    char*  ws    = (char*)d_ws;
    bf16*  qT    = (bf16*)(ws);
    bf16*  kTt   = (bf16*)(ws + 4 * MB);
    bf16*  vTt   = (bf16*)(ws + 8 * MB);
    bf16*  Opart = (bf16*)(ws + 12 * MB);
    bf16*  skipw = (bf16*)(ws + 20 * MB);
    float* S_ws  = (float*)(ws + 24 * MB + 512 * 1024);
    int*   inv   = (int*)(ws + 24 * MB + 512 * 1024 + 256 * 1024);
    bf16*  Wbf   = Opart;   // aliases Opart: read by qkv BEFORE attn writes it

    prep_kernel<<<dim3(160), 256, 0, stream>>>(isel, idrp, Wq, Wk, Wv, Ws, inv, Wbf);
    qkv_mfma_kernel<<<dim3(32, 8, B_), 256, 0, stream>>>(pcd, sel, drop, Wbf,
                                                         qT, kTt, vTt, skipw);
    attn_kernel<<<dim3(128 * 16 * KS_), 64, 0, stream>>>(qT, kTt, vTt, Opart, S_ws);
    scatter_kernel<<<dim3(32, 4, B_), 256, 0, stream>>>(Opart, S_ws, inv, skipw, out);
}

// Round 10
// 117.911 us; speedup vs baseline: 1.7789x; 1.7789x over previous
//
#include <hip/hip_runtime.h>
#include <hip/hip_bf16.h>
#include <math.h>

// Problem constants
#define B_    4
#define C_IN_ 128
#define N_    2048
#define NSEL_ 1024
#define H_    4
#define KS_   2            // key-split chunks (1024 keys = 16 tiles of 64 each)

typedef __bf16 bf16;
typedef __bf16 bf16x2 __attribute__((ext_vector_type(2)));
typedef __bf16 bf16x4 __attribute__((ext_vector_type(4)));
typedef __bf16 bf16x8 __attribute__((ext_vector_type(8)));
typedef float  f32x4  __attribute__((ext_vector_type(4)));

// ---------------------------------------------------------------------------
// Kernel 0 (prep): W fp32 -> bf16 (Wbf, 4x256x128); inverse permutation.
// ---------------------------------------------------------------------------
__global__ __launch_bounds__(256) void prep_kernel(
    const int* __restrict__ isel, const int* __restrict__ idrp,
    const float* __restrict__ Wq, const float* __restrict__ Wk,
    const float* __restrict__ Wv, const float* __restrict__ Ws,
    int* __restrict__ inv, bf16* __restrict__ Wbf)
{
    const int blk = blockIdx.x;
    if (blk < 128) {
        int e = blk * 256 + threadIdx.x;
        int which = e >> 13, idx = e & 8191;
        const float* Wx = (which == 0) ? Wq : (which == 1) ? Wk
                        : (which == 2) ? Wv : Ws;
        float4 v = *(const float4*)(Wx + (size_t)idx * 4);
        bf16x4 o; o[0] = (bf16)v.x; o[1] = (bf16)v.y; o[2] = (bf16)v.z; o[3] = (bf16)v.w;
        *(bf16x4*)(Wbf + (size_t)which * 32768 + (size_t)idx * 4) = o;
    } else {
        int g = (blk - 128) * 256 + threadIdx.x;
        int b = g >> 11, j = g & (N_ - 1);
        int pos = (j < NSEL_) ? isel[b * NSEL_ + j] : idrp[b * NSEL_ + (j - NSEL_)];
        inv[b * N_ + (pos & (N_ - 1))] = j;
    }
}

// ---------------------------------------------------------------------------
// Kernel 1: Q/K/V MFMA GEMM (grid (32, 6, B): which = y>>1 in {0,1,2}).
// Q/K use swapped operands (A=x) -> d-contiguous stores.
// V uses A=W; stored KEY-PERMUTED: slot' = (key&15)*4 + (key>>4), written as
// bf16x4 b64 stores. K slots stay physical. (K slot i <-> V slot sigma(i).)
//   qT : (bh, n, 64) bf16, Q pre-scaled 1/8
//   kTt: (bh, tile, key&63, d) 8KB tiles;  vTt: (bh, tile, dv, slot') 8KB.
// ---------------------------------------------------------------------------
#define XSTR 136

__global__ __launch_bounds__(256) void qkv_mfma_kernel(
    const float* __restrict__ pcd, const float* __restrict__ sel,
    const float* __restrict__ drop, const bf16* __restrict__ Wbf,
    bf16* __restrict__ qT, bf16* __restrict__ kTt, bf16* __restrict__ vTt)
{
    const int ntile = blockIdx.x;
    const int which = blockIdx.y >> 1;   // 0=Q 1=K 2=V
    const int rh    = blockIdx.y & 1;    // 128-row half
    const int b     = blockIdx.z;
    const int tid   = threadIdx.x;
    const int w     = tid >> 6;
    const int lane  = tid & 63;
    const int quad  = lane >> 4;
    const int lc    = lane & 15;
    const int n0    = ntile * 64;

    __shared__ __align__(16) bf16 xT[64 * XSTR];

    const float* srcp; int rstride;
    if (ntile < 16) { srcp = sel  + (size_t)b * C_IN_ * NSEL_ + n0;           rstride = NSEL_; }
    else            { srcp = drop + (size_t)b * C_IN_ * NSEL_ + (n0 - NSEL_); rstride = NSEL_; }

    // Stage x fp32 [c][n] -> bf16 xT [n][c ^ swz]; swz = ((n>>2)&3)<<3.
    #pragma unroll
    for (int k = 0; k < 4; ++k) {
        int e  = tid + k * 256;          // 0..1023
        int cp = e >> 4, nq = e & 15;
        int c0 = cp * 2;
        float4 v0 = *(const float4*)(srcp + (size_t)c0 * rstride + nq * 4);
        float4 v1 = *(const float4*)(srcp + (size_t)(c0 + 1) * rstride + nq * 4);
        int cc = c0 ^ ((nq & 3) << 3);
        float a0[4] = {v0.x, v0.y, v0.z, v0.w};
        float a1[4] = {v1.x, v1.y, v1.z, v1.w};
        #pragma unroll
        for (int i = 0; i < 4; ++i) {
            int n = nq * 4 + i;
            bf16x2 t; t[0] = (bf16)a0[i]; t[1] = (bf16)a1[i];
            *(bf16x2*)&xT[n * XSTR + cc] = t;
        }
    }
    __syncthreads();

    const bf16* wbase = Wbf + (size_t)which * 256 * 128;
    const int rbase = rh * 128 + w * 32;

    f32x4 acc[8];
    #pragma unroll
    for (int i = 0; i < 8; ++i) acc[i] = (f32x4){0.f, 0.f, 0.f, 0.f};

    #pragma unroll
    for (int kq = 0; kq < 4; ++kq) {
        bf16x8 wf[2], xA[4];
        #pragma unroll
        for (int ot = 0; ot < 2; ++ot)
            wf[ot] = *(const bf16x8*)(wbase + (size_t)(rbase + ot * 16 + lc) * 128 + kq * 32 + quad * 8);
        #pragma unroll
        for (int nt = 0; nt < 4; ++nt) {
            int row = nt * 16 + lc;
            int col = (kq * 32 + quad * 8) ^ (((row >> 2) & 3) << 3);
            xA[nt] = *(const bf16x8*)&xT[row * XSTR + col];
        }
        if (which <= 1) {   // swapped: A=x (m=n), B=W (col=o)
            #pragma unroll
            for (int nt = 0; nt < 4; ++nt)
                #pragma unroll
                for (int ot = 0; ot < 2; ++ot)
                    acc[nt * 2 + ot] = __builtin_amdgcn_mfma_f32_16x16x32_bf16(xA[nt], wf[ot], acc[nt * 2 + ot], 0, 0, 0);
        } else {            // V: A=W (m=o), B=x (col=n)
            #pragma unroll
            for (int ot = 0; ot < 2; ++ot)
                #pragma unroll
                for (int nt = 0; nt < 4; ++nt)
                    acc[ot * 4 + nt] = __builtin_amdgcn_mfma_f32_16x16x32_bf16(wf[ot], xA[nt], acc[ot * 4 + nt], 0, 0, 0);
        }
    }

    if (which <= 1) {
        // C: row=n-local (quad*4+r), col=o-local (lc) -> d-contiguous stores.
        #pragma unroll
        for (int nt = 0; nt < 4; ++nt) {
            #pragma unroll
            for (int ot = 0; ot < 2; ++ot) {
                #pragma unroll
                for (int r = 0; r < 4; ++r) {
                    int n    = n0 + nt * 16 + quad * 4 + r;
                    int rloc = nt * 16 + quad * 4 + r;
                    int o256 = rbase + ot * 16 + lc;
                    int h = o256 >> 6, d = o256 & 63;
                    float val = acc[nt * 2 + ot][r];
                    if (which == 0)
                        qT[((size_t)(b * H_ + h) * N_ + n) * 64 + d] = (bf16)(val * 0.125f);
                    else
                        kTt[(((size_t)(b * H_ + h) * 32 + ntile) << 12) | (rloc << 6) | d] = (bf16)val;
                }
            }
        }
    } else {
        // V: C row=o-local (quad*4+r), col=key-local (nt*16+lc).
        // Permuted slot' = lc*4 + nt -> pack 4 nt values into one b64 store.
        #pragma unroll
        for (int ot = 0; ot < 2; ++ot) {
            #pragma unroll
            for (int r = 0; r < 4; ++r) {
                int o256 = rbase + ot * 16 + quad * 4 + r;
                int h = o256 >> 6, dv = o256 & 63;
                bf16x4 pk;
                #pragma unroll
                for (int nt = 0; nt < 4; ++nt) pk[nt] = (bf16)acc[ot * 4 + nt][r];
                *(bf16x4*)(vTt + ((((size_t)(b * H_ + h) * 32 + ntile) << 12) | (dv << 6) | (lc * 4))) = pk;
            }
        }
    }
}

// ---------------------------------------------------------------------------
// Kernel 2: key-split flash attention. Block = 4 waves x 32 queries = 128 q.
// K/V double-buffered in LDS (one barrier/step); P transpose via b64 writes
// into per-wave strip (key-permuted cols). XCD-aware swizzle.
// grid 512 x 256: id -> bh=(id&7)+8*((id>>3)&1), qb=(id>>4)&15, c=id>>8.
// ---------------------------------------------------------------------------
#define PSTR 72
#define KVSTR 72

__global__ __launch_bounds__(256, 2) void attn_kernel(
    const bf16* __restrict__ qT, const bf16* __restrict__ kTt,
    const bf16* __restrict__ vTt, bf16* __restrict__ Opart,
    float* __restrict__ S_ws)
{
    const int id    = blockIdx.x;
    const int bh    = (id & 7) + 8 * ((id >> 3) & 1);
    const int qb    = (id >> 4) & 15;
    const int c     = id >> 8;           // 0..KS_-1
    const int b     = bh >> 2;
    const int h     = bh & 3;
    const int tid   = threadIdx.x;
    const int w     = tid >> 6;
    const int lane  = tid & 63;
    const int quad  = lane >> 4;
    const int lc    = lane & 15;
    const int n0    = qb * 128 + w * 32;

    __shared__ __align__(16) bf16 sK[2][64 * KVSTR];
    __shared__ __align__(16) bf16 sV[2][64 * KVSTR];
    __shared__ __align__(16) bf16 p_lds[4 * 16 * PSTR];
    bf16* pw = &p_lds[w * 16 * PSTR];

    // Q fragments for 2 q-tiles (A layout)
    bf16x8 aq[2][2];
    #pragma unroll
    for (int t = 0; t < 2; ++t) {
        const bf16* qp = qT + ((size_t)bh * N_ + n0 + t * 16 + lc) * 64 + quad * 8;
        aq[t][0] = *(const bf16x8*)(qp);
        aq[t][1] = *(const bf16x8*)(qp + 32);
    }

    const bf16* kbase = kTt + (((size_t)bh * 32 + c * 16) << 12);
    const bf16* vbase = vTt + (((size_t)bh * 32 + c * 16) << 12);

    const int l0 = (tid >> 3) * KVSTR + (tid & 7) * 8;
    const int l1 = ((tid >> 3) + 32) * KVSTR + (tid & 7) * 8;

    // prologue: loads for tile 0
    bf16x8 ldK0 = *(const bf16x8*)(kbase + tid * 8);
    bf16x8 ldK1 = *(const bf16x8*)(kbase + 2048 + tid * 8);
    bf16x8 ldV0 = *(const bf16x8*)(vbase + tid * 8);
    bf16x8 ldV1 = *(const bf16x8*)(vbase + 2048 + tid * 8);

    f32x4 accO[2][4];
    #pragma unroll
    for (int t = 0; t < 2; ++t)
        #pragma unroll
        for (int i = 0; i < 4; ++i) accO[t][i] = (f32x4){0.f, 0.f, 0.f, 0.f};
    float psum[2][4] = {{0.f,0.f,0.f,0.f},{0.f,0.f,0.f,0.f}};

    for (int s = 0; s < 16; ++s) {
        const int buf = s & 1;
        // write staged regs -> buf (prev-step barrier guarantees no readers)
        *(bf16x8*)&sK[buf][l0] = ldK0;
        *(bf16x8*)&sK[buf][l1] = ldK1;
        *(bf16x8*)&sV[buf][l0] = ldV0;
        *(bf16x8*)&sV[buf][l1] = ldV1;
        __syncthreads();               // one barrier per step

        if (s < 15) {                  // issue next tile's loads; land during compute
            const bf16* kg = kbase + ((size_t)(s + 1) << 12);
            const bf16* vg = vbase + ((size_t)(s + 1) << 12);
            ldK0 = *(const bf16x8*)(kg + tid * 8);
            ldK1 = *(const bf16x8*)(kg + 2048 + tid * 8);
            ldV0 = *(const bf16x8*)(vg + tid * 8);
            ldV1 = *(const bf16x8*)(vg + 2048 + tid * 8);
        }

        // fragments (shared by both q-tiles)
        bf16x8 kf[4][2], vf[4][2];
        #pragma unroll
        for (int mt = 0; mt < 4; ++mt) {
            const int rb = (mt * 16 + lc) * KVSTR + quad * 8;
            kf[mt][0] = *(const bf16x8*)&sK[buf][rb];
            kf[mt][1] = *(const bf16x8*)&sK[buf][rb + 32];
            vf[mt][0] = *(const bf16x8*)&sV[buf][rb];
            vf[mt][1] = *(const bf16x8*)&sV[buf][rb + 32];
        }

        #pragma unroll
        for (int t = 0; t < 2; ++t) {
            // ---- S ----
            f32x4 accS[4];
            #pragma unroll
            for (int mt = 0; mt < 4; ++mt) {
                f32x4 z = (f32x4){0.f, 0.f, 0.f, 0.f};
                z = __builtin_amdgcn_mfma_f32_16x16x32_bf16(aq[t][0], kf[mt][0], z, 0, 0, 0);
                z = __builtin_amdgcn_mfma_f32_16x16x32_bf16(aq[t][1], kf[mt][1], z, 0, 0, 0);
                accS[mt] = z;
            }
            // ---- P = exp(S), per-lane partial sums ----
            #pragma unroll
            for (int r = 0; r < 4; ++r) {
                float sum = 0.f;
                #pragma unroll
                for (int mt = 0; mt < 4; ++mt) {
                    float p = __expf(accS[mt][r]);
                    accS[mt][r] = p;
                    sum += p;
                }
                psum[t][r] += sum;
            }
            // ---- P -> LDS strip at permuted cols lc*4+mt: b64 writes ----
            #pragma unroll
            for (int r = 0; r < 4; ++r) {
                bf16x4 pk;
                #pragma unroll
                for (int mt = 0; mt < 4; ++mt) pk[mt] = (bf16)accS[mt][r];
                *(bf16x4*)&pw[(quad * 4 + r) * PSTR + lc * 4] = pk;
            }
            bf16x8 ap0 = *(const bf16x8*)(&pw[lc * PSTR + quad * 8]);
            bf16x8 ap1 = *(const bf16x8*)(&pw[lc * PSTR + 32 + quad * 8]);
            // ---- O += P * V^T (V pre-permuted to match) ----
            #pragma unroll
            for (int dvt = 0; dvt < 4; ++dvt) {
                accO[t][dvt] = __builtin_amdgcn_mfma_f32_16x16x32_bf16(ap0, vf[dvt][0], accO[t][dvt], 0, 0, 0);
                accO[t][dvt] = __builtin_amdgcn_mfma_f32_16x16x32_bf16(ap1, vf[dvt][1], accO[t][dvt], 0, 0, 0);
            }
        }
    }

    // ---- chunk denominators + chunk-normalized O ----
    #pragma unroll
    for (int t = 0; t < 2; ++t) {
        float inv[4];
        #pragma unroll
        for (int r = 0; r < 4; ++r) {
            float s = psum[t][r];
            #pragma unroll
            for (int off = 1; off < 16; off <<= 1)
                s += __shfl_xor(s, off, 64);
            inv[r] = 1.f / s;
            int n = n0 + t * 16 + quad * 4 + r;
            if (lc == 0)
                S_ws[((size_t)(c * B_ + b) * H_ + h) * N_ + n] = s;
        }
        #pragma unroll
        for (int r = 0; r < 4; ++r) {
            int n = n0 + t * 16 + quad * 4 + r;
            #pragma unroll
            for (int dvt = 0; dvt < 4; ++dvt) {
                int o = h * 64 + dvt * 16 + lc;
                Opart[((size_t)(c * B_ + b) * N_ + n) * 256 + o] = (bf16)(accO[t][dvt][r] * inv[r]);
            }
        }
    }
}

// ---------------------------------------------------------------------------
// Kernel 3: skip GEMM (destination order, no permutation!) + KS-chunk merge +
// permutation gather. out = skip + sum_c w_c*Opart[c][inv[pos]].
// grid (32 pos-tiles, 4 og(=h), B), 256 thr.
// ---------------------------------------------------------------------------
__global__ __launch_bounds__(256) void scatter_kernel(
    const bf16* __restrict__ Opart, const float* __restrict__ S_ws,
    const int* __restrict__ inv, const float* __restrict__ pcd,
    const bf16* __restrict__ Wbf, float* __restrict__ out)
{
    const int ptile = blockIdx.x;
    const int og    = blockIdx.y;     // == head h
    const int b     = blockIdx.z;
    const int tid   = threadIdx.x;
    const int w     = tid >> 6;
    const int lane  = tid & 63;
    const int quad  = lane >> 4;
    const int lc    = lane & 15;
    const int p0    = ptile * 64;

    __shared__ __align__(16) bf16 xT[64 * XSTR];    // pcd tile (dest order)
    __shared__ __align__(16) bf16 lds[64 * 72];     // merged attn [pos][o_loc]
    __shared__ float wls[KS_][64];
    __shared__ int   jrow[64];

    // stage pcd fp32 [c][pos] -> bf16 xT [pos][c^swz]
    const float* srcp = pcd + (size_t)b * C_IN_ * N_ + p0;
    #pragma unroll
    for (int k = 0; k < 4; ++k) {
        int e  = tid + k * 256;
        int cp = e >> 4, nq = e & 15;
        int c0 = cp * 2;
        float4 v0 = *(const float4*)(srcp + (size_t)c0 * N_ + nq * 4);
        float4 v1 = *(const float4*)(srcp + (size_t)(c0 + 1) * N_ + nq * 4);
        int cc = c0 ^ ((nq & 3) << 3);
        float a0[4] = {v0.x, v0.y, v0.z, v0.w};
        float a1[4] = {v1.x, v1.y, v1.z, v1.w};
        #pragma unroll
        for (int i = 0; i < 4; ++i) {
            int n = nq * 4 + i;
            bf16x2 t; t[0] = (bf16)a0[i]; t[1] = (bf16)a1[i];
            *(bf16x2*)&xT[n * XSTR + cc] = t;
        }
    }
    if (tid < 64) {
        int row = tid;
        int j = inv[b * N_ + p0 + row] & (N_ - 1);
        jrow[row] = j;
        float sv[KS_]; float denom = 0.f;
        #pragma unroll
        for (int c = 0; c < KS_; ++c) {
            sv[c] = S_ws[((size_t)(c * B_ + b) * H_ + og) * N_ + j];
            denom += sv[c];
        }
        float idn = 1.f / denom;
        #pragma unroll
        for (int c = 0; c < KS_; ++c) wls[c][row] = sv[c] * idn;
    }
    __syncthreads();

    // skip GEMM: rows og*64 + w*16 .. +15, cols p0..p0+63, K=128 (A=W swapped? A=W normal)
    const bf16* wbase = Wbf + (size_t)3 * 256 * 128 + (size_t)(og * 64 + w * 16) * 128;
    f32x4 acc[4];
    #pragma unroll
    for (int i = 0; i < 4; ++i) acc[i] = (f32x4){0.f, 0.f, 0.f, 0.f};
    #pragma unroll
    for (int kq = 0; kq < 4; ++kq) {
        bf16x8 A = *(const bf16x8*)(wbase + (size_t)lc * 128 + kq * 32 + quad * 8);
        #pragma unroll
        for (int nt = 0; nt < 4; ++nt) {
            int row = nt * 16 + lc;
            int col = (kq * 32 + quad * 8) ^ (((row >> 2) & 3) << 3);
            bf16x8 Bf = *(const bf16x8*)&xT[row * XSTR + col];
            acc[nt] = __builtin_amdgcn_mfma_f32_16x16x32_bf16(A, Bf, acc[nt], 0, 0, 0);
        }
    }

    // merge KS chunks into lds[pos][o_loc]
    #pragma unroll
    for (int k = 0; k < 2; ++k) {
        int e = tid + k * 256;
        int row = e >> 3, seg = e & 7;
        int j = jrow[row];
        float a8[8];
        #pragma unroll
        for (int i = 0; i < 8; ++i) a8[i] = 0.f;
        #pragma unroll
        for (int c = 0; c < KS_; ++c) {
            bf16x8 v = *(const bf16x8*)(Opart + ((size_t)(c * B_ + b) * N_ + j) * 256 + og * 64 + seg * 8);
            float wgt = wls[c][row];
            #pragma unroll
            for (int i = 0; i < 8; ++i) a8[i] += wgt * (float)v[i];
        }
        bf16x8 o8;
        #pragma unroll
        for (int i = 0; i < 8; ++i) o8[i] = (bf16)a8[i];
        *(bf16x8*)&lds[row * 72 + seg * 8] = o8;
    }
    __syncthreads();

    // combine: out = skip(acc, C layout row=quad*4+r o-local, col=nt*16+lc pos)
    //              + lds[pos][o_loc]
    #pragma unroll
    for (int nt = 0; nt < 4; ++nt) {
        #pragma unroll
        for (int r = 0; r < 4; ++r) {
            int o_loc = w * 16 + quad * 4 + r;
            int p     = nt * 16 + lc;
            float attn = (float)lds[p * 72 + o_loc];
            out[((size_t)b * 256 + og * 64 + o_loc) * N_ + p0 + p] = acc[nt][r] + attn;
        }
    }
}

// ---------------------------------------------------------------------------
extern "C" void kernel_launch(void* const* d_in, const int* in_sizes, int n_in,
                              void* d_out, int out_size, void* d_ws, size_t ws_size,
                              hipStream_t stream) {
    const float* pcd  = (const float*)d_in[0];
    const float* sel  = (const float*)d_in[1];
    const float* drop = (const float*)d_in[2];
    const int*   isel = (const int*)d_in[3];
    const int*   idrp = (const int*)d_in[4];
    const float* Wq   = (const float*)d_in[5];
    const float* Wk   = (const float*)d_in[6];
    const float* Wv   = (const float*)d_in[7];
    const float* Ws   = (const float*)d_in[8];
    float* out = (float*)d_out;

    const size_t MB = 1024 * 1024;
    // ws: qT 4 | kTt 4 | vTt 4 | Opart 8 | S_ws 256K | Wbf 256K | inv 32K
    char*  ws    = (char*)d_ws;
    bf16*  qT    = (bf16*)(ws);
    bf16*  kTt   = (bf16*)(ws + 4 * MB);
    bf16*  vTt   = (bf16*)(ws + 8 * MB);
    bf16*  Opart = (bf16*)(ws + 12 * MB);
    float* S_ws  = (float*)(ws + 20 * MB);
    bf16*  Wbf   = (bf16*)(ws + 20 * MB + 256 * 1024);
    int*   inv   = (int*)(ws + 20 * MB + 512 * 1024);

    prep_kernel<<<dim3(160), 256, 0, stream>>>(isel, idrp, Wq, Wk, Wv, Ws, inv, Wbf);
    qkv_mfma_kernel<<<dim3(32, 6, B_), 256, 0, stream>>>(pcd, sel, drop, Wbf,
                                                         qT, kTt, vTt);
    attn_kernel<<<dim3(16 * 16 * KS_), 256, 0, stream>>>(qT, kTt, vTt, Opart, S_ws);
    scatter_kernel<<<dim3(32, 4, B_), 256, 0, stream>>>(Opart, S_ws, inv, pcd, Wbf, out);
}